// Round 1
// baseline (46.155 us; speedup 1.0000x reference)
//
#include <hip/hip_runtime.h>
#include <math.h>

// Sparsemax along last axis, rows of N=4096 f32.
// One 256-thread block per row. Each thread holds 16 elements in registers
// (4x float4, coalesced). Support of sparsemax is contained in {z > max-1},
// so we gather that small candidate set to LDS, bitonic-sort it (descending),
// and replicate the reference's masked-cumsum tau formulation serially.

#define NCOL 4096
#define CAP 1024
#define BLK 256

__global__ __launch_bounds__(BLK) void sparsemax_kernel(const float* __restrict__ in,
                                                        float* __restrict__ out) {
    const int row = blockIdx.x;
    const int tid = threadIdx.x;
    const float4* in4 = (const float4*)(in + (size_t)row * NCOL);
    float4* out4 = (float4*)(out + (size_t)row * NCOL);

    // ---- load 16 elems/thread, track local max ----
    float4 v[4];
    float m = -INFINITY;
#pragma unroll
    for (int i = 0; i < 4; ++i) {
        v[i] = in4[tid + i * BLK];
        m = fmaxf(m, fmaxf(fmaxf(v[i].x, v[i].y), fmaxf(v[i].z, v[i].w)));
    }

    // ---- block max reduction ----
#pragma unroll
    for (int off = 32; off > 0; off >>= 1)
        m = fmaxf(m, __shfl_xor(m, off, 64));

    __shared__ float wmax[4];
    __shared__ float sh_cand[CAP];
    __shared__ int sh_count;
    __shared__ float sh_tau;

    const int lane = tid & 63, wid = tid >> 6;
    if (lane == 0) wmax[wid] = m;
    if (tid == 0) sh_count = 0;
    __syncthreads();
    const float rowmax = fmaxf(fmaxf(wmax[0], wmax[1]), fmaxf(wmax[2], wmax[3]));
    const float thr = rowmax - 1.0f;  // support is strictly above this

    // ---- gather candidates into LDS ----
#pragma unroll
    for (int i = 0; i < 4; ++i) {
        float vals[4] = {v[i].x, v[i].y, v[i].z, v[i].w};
#pragma unroll
        for (int j = 0; j < 4; ++j) {
            if (vals[j] > thr) {
                int idx = atomicAdd(&sh_count, 1);
                if (idx < CAP) sh_cand[idx] = vals[j];
            }
        }
    }
    __syncthreads();
    const int count = min(sh_count, CAP);

    // pad to next pow2 with -inf
    int P = 1;
    while (P < count) P <<= 1;
    for (int i = count + tid; i < P; i += BLK) sh_cand[i] = -INFINITY;
    __syncthreads();

    // ---- bitonic sort descending on P elements ----
    for (int k = 2; k <= P; k <<= 1) {
        for (int j = k >> 1; j > 0; j >>= 1) {
            for (int i = tid; i < P; i += BLK) {
                int ixj = i ^ j;
                if (ixj > i) {
                    float a = sh_cand[i], b = sh_cand[ixj];
                    bool up = ((i & k) == 0);  // descending block for overall descending
                    if (up ? (a < b) : (a > b)) { sh_cand[i] = b; sh_cand[ixj] = a; }
                }
            }
            __syncthreads();
        }
    }

    // ---- serial tau (replicates reference's tau_sum = sum of masked cumsum) ----
    if (tid == 0) {
        float cs = 0.0f, ts = 0.0f;
        int kk = 0;
        for (int j = 0; j < count; ++j) {
            float z = sh_cand[j];
            cs += z;
            if ((float)(j + 1) * z > cs - 1.0f) { ++kk; ts += cs; }
            // beyond candidates the mask is provably false: z_(j) <= max-1
            // implies sum_{i<=j}(z_(i)-z_(j)) >= 1.
        }
        sh_tau = (ts - 1.0f) / (float)(kk > 1 ? kk : 1);
    }
    __syncthreads();
    const float tau = sh_tau;

    // ---- write out = max(z - tau, 0) from registers ----
#pragma unroll
    for (int i = 0; i < 4; ++i) {
        float4 o;
        o.x = fmaxf(v[i].x - tau, 0.0f);
        o.y = fmaxf(v[i].y - tau, 0.0f);
        o.z = fmaxf(v[i].z - tau, 0.0f);
        o.w = fmaxf(v[i].w - tau, 0.0f);
        out4[tid + i * BLK] = o;
    }
}

extern "C" void kernel_launch(void* const* d_in, const int* in_sizes, int n_in,
                              void* d_out, int out_size, void* d_ws, size_t ws_size,
                              hipStream_t stream) {
    const float* in = (const float*)d_in[0];
    float* out = (float*)d_out;
    const int rows = in_sizes[0] / NCOL;  // 4*2048 = 8192
    sparsemax_kernel<<<rows, BLK, 0, stream>>>(in, out);
}

// Round 2
// 45.491 us; speedup vs baseline: 1.0146x; 1.0146x over previous
//
#include <hip/hip_runtime.h>
#include <math.h>

// Sparsemax along last axis, rows of N=4096 f32.
// One 256-thread block per row. 16 elems/thread in registers (4x float4).
// Support of sparsemax is contained in {z > max-1} (since for z_(j) <= max-1,
// sum_{i<=j}(z_(i)-z_(j)) >= z_(1)-z_(j) >= 1, violating the support cond).
// Gather that small candidate set; if it fits in one wave (<=64, the common
// case ~30), sort it in registers with a shfl_xor bitonic network (no
// barriers) and run the reference's exact sequential masked-cumsum tau scan.
// Fallback: LDS bitonic up to 1024 candidates.

#define NCOL 4096
#define CAP 1024
#define BLK 256

__global__ __launch_bounds__(BLK) void sparsemax_kernel(const float* __restrict__ in,
                                                        float* __restrict__ out) {
    const int row = blockIdx.x;
    const int tid = threadIdx.x;
    const float4* in4 = (const float4*)(in + (size_t)row * NCOL);
    float4* out4 = (float4*)(out + (size_t)row * NCOL);

    // ---- load 16 elems/thread, track local max ----
    float4 v[4];
    float m = -INFINITY;
#pragma unroll
    for (int i = 0; i < 4; ++i) {
        v[i] = in4[tid + i * BLK];
        m = fmaxf(m, fmaxf(fmaxf(v[i].x, v[i].y), fmaxf(v[i].z, v[i].w)));
    }

    // ---- wave max reduction ----
#pragma unroll
    for (int off = 32; off > 0; off >>= 1)
        m = fmaxf(m, __shfl_xor(m, off, 64));

    __shared__ float wmax[4];
    __shared__ float sh_cand[CAP];
    __shared__ int sh_count;
    __shared__ float sh_tau;

    const int lane = tid & 63, wid = tid >> 6;
    if (lane == 0) wmax[wid] = m;
    if (tid == 0) sh_count = 0;
    __syncthreads();
    const float rowmax = fmaxf(fmaxf(wmax[0], wmax[1]), fmaxf(wmax[2], wmax[3]));
    const float thr = rowmax - 1.0f;  // support is strictly above this

    // ---- gather candidates into LDS ----
#pragma unroll
    for (int i = 0; i < 4; ++i) {
        float vals[4] = {v[i].x, v[i].y, v[i].z, v[i].w};
#pragma unroll
        for (int j = 0; j < 4; ++j) {
            if (vals[j] > thr) {
                int idx = atomicAdd(&sh_count, 1);
                if (idx < CAP) sh_cand[idx] = vals[j];
            }
        }
    }
    __syncthreads();
    const int count = min(sh_count, CAP);  // block-uniform

    if (count <= 64) {
        // ===== fast path: wave-0 in-register bitonic, zero barriers =====
        if (wid == 0) {
            float z = (lane < count) ? sh_cand[lane] : -INFINITY;
            // 64-lane bitonic sort, descending
#pragma unroll
            for (int k = 2; k <= 64; k <<= 1) {
#pragma unroll
                for (int j = k >> 1; j > 0; j >>= 1) {
                    float p = __shfl_xor(z, j, 64);
                    bool up = ((lane & k) == 0);     // descending block
                    bool lower = ((lane & j) == 0);
                    float mx = fmaxf(z, p), mn = fminf(z, p);
                    z = (up == lower) ? mx : mn;
                }
            }
            // serial tau scan (exact sequential f32 order, all lanes redundant)
            float cs = 0.0f, ts = 0.0f;
            int kk = 0;
            for (int j = 0; j < count; ++j) {
                float zz = __shfl(z, j, 64);
                cs += zz;
                if ((float)(j + 1) * zz > cs - 1.0f) { ++kk; ts += cs; }
            }
            if (lane == 0) sh_tau = (ts - 1.0f) / (float)(kk > 1 ? kk : 1);
        }
    } else {
        // ===== general path: LDS bitonic up to CAP =====
        int P = 1;
        while (P < count) P <<= 1;
        for (int i = count + tid; i < P; i += BLK) sh_cand[i] = -INFINITY;
        __syncthreads();
        for (int k = 2; k <= P; k <<= 1) {
            for (int j = k >> 1; j > 0; j >>= 1) {
                for (int i = tid; i < P; i += BLK) {
                    int ixj = i ^ j;
                    if (ixj > i) {
                        float a = sh_cand[i], b = sh_cand[ixj];
                        bool up = ((i & k) == 0);
                        if (up ? (a < b) : (a > b)) { sh_cand[i] = b; sh_cand[ixj] = a; }
                    }
                }
                __syncthreads();
            }
        }
        if (tid == 0) {
            float cs = 0.0f, ts = 0.0f;
            int kk = 0;
            for (int j = 0; j < count; ++j) {
                float zz = sh_cand[j];
                cs += zz;
                if ((float)(j + 1) * zz > cs - 1.0f) { ++kk; ts += cs; }
            }
            sh_tau = (ts - 1.0f) / (float)(kk > 1 ? kk : 1);
        }
    }
    __syncthreads();
    const float tau = sh_tau;

    // ---- write out = max(z - tau, 0) from registers ----
#pragma unroll
    for (int i = 0; i < 4; ++i) {
        float4 o;
        o.x = fmaxf(v[i].x - tau, 0.0f);
        o.y = fmaxf(v[i].y - tau, 0.0f);
        o.z = fmaxf(v[i].z - tau, 0.0f);
        o.w = fmaxf(v[i].w - tau, 0.0f);
        out4[tid + i * BLK] = o;
    }
}

extern "C" void kernel_launch(void* const* d_in, const int* in_sizes, int n_in,
                              void* d_out, int out_size, void* d_ws, size_t ws_size,
                              hipStream_t stream) {
    const float* in = (const float*)d_in[0];
    float* out = (float*)d_out;
    const int rows = in_sizes[0] / NCOL;  // 4*2048 = 8192
    sparsemax_kernel<<<rows, BLK, 0, stream>>>(in, out);
}

// Round 4
// 44.672 us; speedup vs baseline: 1.0332x; 1.0183x over previous
//
#include <hip/hip_runtime.h>
#include <math.h>

// Sparsemax along last axis, rows of N=4096 f32.
// One 256-thread block per row. 16 elems/thread in registers (4x float4).
// Support of sparsemax is contained in {z > max-1}. Gather that small
// candidate set (~30 elems); wave-0 sorts it in registers via shfl_xor
// bitonic (no barriers) and runs the reference's exact sequential
// masked-cumsum tau scan. Fallback: LDS bitonic up to 1024 candidates.
// Output stores are NON-TEMPORAL so the streamed output doesn't evict the
// (re-read-across-replays) input from the 256 MiB Infinity Cache.

#define NCOL 4096
#define CAP 1024
#define BLK 256

typedef float f32x4 __attribute__((ext_vector_type(4)));

__global__ __launch_bounds__(BLK) void sparsemax_kernel(const float* __restrict__ in,
                                                        float* __restrict__ out) {
    const int row = blockIdx.x;
    const int tid = threadIdx.x;
    const float4* in4 = (const float4*)(in + (size_t)row * NCOL);
    f32x4* out4 = (f32x4*)(out + (size_t)row * NCOL);

    // ---- load 16 elems/thread, track local max ----
    float4 v[4];
    float m = -INFINITY;
#pragma unroll
    for (int i = 0; i < 4; ++i) {
        v[i] = in4[tid + i * BLK];
        m = fmaxf(m, fmaxf(fmaxf(v[i].x, v[i].y), fmaxf(v[i].z, v[i].w)));
    }

    // ---- wave max reduction ----
#pragma unroll
    for (int off = 32; off > 0; off >>= 1)
        m = fmaxf(m, __shfl_xor(m, off, 64));

    __shared__ float wmax[4];
    __shared__ float sh_cand[CAP];
    __shared__ int sh_count;
    __shared__ float sh_tau;

    const int lane = tid & 63, wid = tid >> 6;
    if (lane == 0) wmax[wid] = m;
    if (tid == 0) sh_count = 0;
    __syncthreads();
    const float rowmax = fmaxf(fmaxf(wmax[0], wmax[1]), fmaxf(wmax[2], wmax[3]));
    const float thr = rowmax - 1.0f;  // support is strictly above this

    // ---- gather candidates into LDS ----
#pragma unroll
    for (int i = 0; i < 4; ++i) {
        float vals[4] = {v[i].x, v[i].y, v[i].z, v[i].w};
#pragma unroll
        for (int j = 0; j < 4; ++j) {
            if (vals[j] > thr) {
                int idx = atomicAdd(&sh_count, 1);
                if (idx < CAP) sh_cand[idx] = vals[j];
            }
        }
    }
    __syncthreads();
    const int count = min(sh_count, CAP);  // block-uniform

    if (count <= 64) {
        // ===== fast path: wave-0 in-register bitonic, zero barriers =====
        if (wid == 0) {
            float z = (lane < count) ? sh_cand[lane] : -INFINITY;
#pragma unroll
            for (int k = 2; k <= 64; k <<= 1) {
#pragma unroll
                for (int j = k >> 1; j > 0; j >>= 1) {
                    float p = __shfl_xor(z, j, 64);
                    bool up = ((lane & k) == 0);
                    bool lower = ((lane & j) == 0);
                    float mx = fmaxf(z, p), mn = fminf(z, p);
                    z = (up == lower) ? mx : mn;
                }
            }
            // serial tau scan (exact sequential f32 order, all lanes redundant)
            float cs = 0.0f, ts = 0.0f;
            int kk = 0;
            for (int j = 0; j < count; ++j) {
                float zz = __shfl(z, j, 64);
                cs += zz;
                if ((float)(j + 1) * zz > cs - 1.0f) { ++kk; ts += cs; }
            }
            if (lane == 0) sh_tau = (ts - 1.0f) / (float)(kk > 1 ? kk : 1);
        }
    } else {
        // ===== general path: LDS bitonic up to CAP =====
        int P = 1;
        while (P < count) P <<= 1;
        for (int i = count + tid; i < P; i += BLK) sh_cand[i] = -INFINITY;
        __syncthreads();
        for (int k = 2; k <= P; k <<= 1) {
            for (int j = k >> 1; j > 0; j >>= 1) {
                for (int i = tid; i < P; i += BLK) {
                    int ixj = i ^ j;
                    if (ixj > i) {
                        float a = sh_cand[i], b = sh_cand[ixj];
                        bool up = ((i & k) == 0);
                        if (up ? (a < b) : (a > b)) { sh_cand[i] = b; sh_cand[ixj] = a; }
                    }
                }
                __syncthreads();
            }
        }
        if (tid == 0) {
            float cs = 0.0f, ts = 0.0f;
            int kk = 0;
            for (int j = 0; j < count; ++j) {
                float zz = sh_cand[j];
                cs += zz;
                if ((float)(j + 1) * zz > cs - 1.0f) { ++kk; ts += cs; }
            }
            sh_tau = (ts - 1.0f) / (float)(kk > 1 ? kk : 1);
        }
    }
    __syncthreads();
    const float tau = sh_tau;

    // ---- write out = max(z - tau, 0), non-temporal (don't evict input from L3) ----
#pragma unroll
    for (int i = 0; i < 4; ++i) {
        f32x4 o;
        o.x = fmaxf(v[i].x - tau, 0.0f);
        o.y = fmaxf(v[i].y - tau, 0.0f);
        o.z = fmaxf(v[i].z - tau, 0.0f);
        o.w = fmaxf(v[i].w - tau, 0.0f);
        __builtin_nontemporal_store(o, &out4[tid + i * BLK]);
    }
}

extern "C" void kernel_launch(void* const* d_in, const int* in_sizes, int n_in,
                              void* d_out, int out_size, void* d_ws, size_t ws_size,
                              hipStream_t stream) {
    const float* in = (const float*)d_in[0];
    float* out = (float*)d_out;
    const int rows = in_sizes[0] / NCOL;  // 4*2048 = 8192
    sparsemax_kernel<<<rows, BLK, 0, stream>>>(in, out);
}